// Round 16
// baseline (6665.892 us; speedup 1.0000x reference)
//
#include <hip/hip_runtime.h>

// SpikeMLP — R27: 16x8 tile, k-major LDS (0-conflict family) + bijective
// W-chunk interleave + amdgpu_waves_per_eu(2,2) allocator pin.
// Chain contract (FROZEN, verified absmax=0.0 @ R14-R16,R18-R26):
//   per C element: acc = fma(a_k, w_k, acc), k = 0..1023 strictly
//   ascending, single accumulator, fp32, contract off. Recurrence fp32
//   ufunc order. MFMA / k-reassoc / packed-fp32 (R22 half-rate) forbidden.
// R26 post-mortem: 1.26e8 bank conflicts (stride-33 pad breaks b128
//   writes; chunk-XOR collided 8-way on staging) + allocator granted 128
//   for need ~210 (chose 4 waves/EU, spilled acc into L2-absorbed
//   scratch). DS-ratio theory intact: 8x8 = 1.5x DS-over (the 1600us
//   plateau), 16x8 = 1.13x.
// R27 fixes:
//   - k-major As[32][256], Ws[32][128] with R14-R21's b32-column staging
//     (measured 0 conflicts across 10 rounds).
//   - W col map n=4c+l -> word ((c&1)<<6)|((c>>1)<<2)|l  (bijective):
//     read chunks of thread tx at words tx*4 and 64+tx*4 (2-way free);
//     staging writes 2-way free (mod-32: 4*(c>>1)+l covers 0..31 x2).
//   - amdgpu_waves_per_eu(2,2): allocator targets exactly 2 waves/EU ->
//     uses up to 256 VGPR, no occupancy-chasing spills.
// Predicted: VGPR ~190-230 (128 again => attribute defeated => 12x8
//   next), BANK_CONFLICT ~0, WRITE 262144 KB, Occ ~25%, VALUBusy 75-85%,
//   big GEMM ~1150-1300us, total ~2.9-3.1ms, absmax 0.0.

typedef float floatx4 __attribute__((ext_vector_type(4)));

static constexpr int BSZ   = 4096;
static constexpr int D_IN  = 1024;
static constexpr int H1    = 1024;
static constexpr int D_OUT = 512;
static constexpr int M_ROWS = BSZ * 16;   // 65536, m = b*16 + t

// ---------------------------------------------------------------------------
// pack X [B, D_in, T=16] f32 -> A [m = b*16 + t][d] f32 (spikes exactly 0/1)
// ---------------------------------------------------------------------------
__global__ void pack_x(const float* __restrict__ X, float* __restrict__ A) {
    const int P = blockIdx.x * 256 + threadIdx.x;     // P = b*1024 + d
    const int b = P >> 10, d = P & 1023;
    const float4* xp = (const float4*)(X + (size_t)P * 16);
    float4 x0 = xp[0], x1 = xp[1], x2 = xp[2], x3 = xp[3];
    const float v[16] = {x0.x, x0.y, x0.z, x0.w, x1.x, x1.y, x1.z, x1.w,
                         x2.x, x2.y, x2.z, x2.w, x3.x, x3.y, x3.z, x3.w};
#pragma unroll
    for (int t = 0; t < 16; ++t)
        A[((size_t)(b * 16 + t)) * 1024 + d] = v[t];
}

// W LDS column interleave: n = 4c + l  ->  word ((c&1)<<6)|((c>>1)<<2)|l
__device__ __forceinline__ int wcol(int n) {
    const int c = n >> 2, l = n & 3;
    return ((c & 1) << 6) | ((c >> 1) << 2) | l;
}

// ---------------------------------------------------------------------------
// GEMM, reference fp32 chain. C[m][n] = A[m,:] . W[n,:], K = 1024.
// Block 256(M) x 128(N), 256 threads, 16x8 per thread. BK = 32.
// k-major LDS, single buffer, 2 barriers/tile (R21 cadence).
// Thread (tx,ty): rows ty*16..+15, cols tx*8..+7 (= chunks 2tx, 2tx+1).
// Single ascending accumulator over full K (frozen chain).
// ---------------------------------------------------------------------------
__global__ __launch_bounds__(256)
__attribute__((amdgpu_waves_per_eu(2, 2)))
void gemm_np(
    const float* __restrict__ A,    // [M, 1024] f32 spikes (exactly 0/1)
    const float* __restrict__ W,    // [N, 1024] f32 weights (raw input)
    float* __restrict__ C,          // [M, N] fp32
    int N) {
#pragma clang fp contract(off)
    __shared__ float As[32][256];   // [kk][m]  32 KB
    __shared__ float Ws[32][128];   // [kk][wcol(n)]  16 KB

    const int tid = threadIdx.x;
    const int tx = tid & 15;        // col group: cols tx*8 .. +7
    const int ty = tid >> 4;        // row group: rows ty*16 .. +15
    const int m0 = blockIdx.x * 256, n0 = blockIdx.y * 128;

    // staging: A one row per thread; W half-row per thread
    const float* Ag = A + (size_t)(m0 + tid) * 1024;
    const int wn = tid & 127, wkh = (tid >> 7) * 16;
    const float* Wg = W + (size_t)(n0 + wn) * 1024 + wkh;
    const int wc = wcol(wn);

    float acc[16][8] = {};   // single-chain accumulators

    for (int kt = 0; kt < 32; ++kt) {
        const int k0 = kt * 32;
        // global reads (issue before barrier; R21 cadence)
        floatx4 av[8], wv[4];
#pragma unroll
        for (int c = 0; c < 8; ++c)
            av[c] = *(const floatx4*)(Ag + k0 + c * 4);
#pragma unroll
        for (int q = 0; q < 4; ++q)
            wv[q] = *(const floatx4*)(Wg + k0 + q * 4);
        __syncthreads();             // previous tile fully consumed
#pragma unroll
        for (int c = 0; c < 8; ++c)
#pragma unroll
            for (int e = 0; e < 4; ++e)
                As[c * 4 + e][tid] = av[c][e];        // b32 col-writes, 2-way
#pragma unroll
        for (int q = 0; q < 4; ++q)
#pragma unroll
            for (int e = 0; e < 4; ++e)
                Ws[wkh + q * 4 + e][wc] = wv[q][e];   // b32 col-writes, 2-way
        __syncthreads();

        // compute: kk ascending; one FMA per element per k (frozen)
#pragma unroll
        for (int kk = 0; kk < 32; ++kk) {
            floatx4 w0 = *(const floatx4*)&Ws[kk][tx * 4];       // cols tx*8..+3
            floatx4 w1 = *(const floatx4*)&Ws[kk][64 + tx * 4];  // cols tx*8+4..+7
#pragma unroll
            for (int c = 0; c < 4; ++c) {
                floatx4 a4 = *(const floatx4*)&As[kk][ty * 16 + c * 4];
#pragma unroll
                for (int e = 0; e < 4; ++e) {
                    const float ai = a4[e];
                    const int i = c * 4 + e;
                    acc[i][0] = __builtin_fmaf(ai, w0[0], acc[i][0]);
                    acc[i][1] = __builtin_fmaf(ai, w0[1], acc[i][1]);
                    acc[i][2] = __builtin_fmaf(ai, w0[2], acc[i][2]);
                    acc[i][3] = __builtin_fmaf(ai, w0[3], acc[i][3]);
                    acc[i][4] = __builtin_fmaf(ai, w1[0], acc[i][4]);
                    acc[i][5] = __builtin_fmaf(ai, w1[1], acc[i][5]);
                    acc[i][6] = __builtin_fmaf(ai, w1[2], acc[i][6]);
                    acc[i][7] = __builtin_fmaf(ai, w1[3], acc[i][7]);
                }
            }
        }
    }

#pragma unroll
    for (int i = 0; i < 16; ++i) {
        floatx4 s0 = {acc[i][0], acc[i][1], acc[i][2], acc[i][3]};
        floatx4 s1 = {acc[i][4], acc[i][5], acc[i][6], acc[i][7]};
        float* cp = C + (size_t)(m0 + ty * 16 + i) * N + n0 + tx * 8;
        *(floatx4*)cp       = s0;
        *(floatx4*)(cp + 4) = s1;
    }
}

// ---------------------------------------------------------------------------
// fp32 LIF recurrence, numpy ufunc order, contraction off (frozen).
// In-place: Z holds GEMM output, overwritten with f32 spikes (exact 0/1).
// ---------------------------------------------------------------------------
__global__ void recur_hidden(float* __restrict__ Z, const float* __restrict__ bias) {
#pragma clang fp contract(off)
    const int idx = blockIdx.x * 256 + threadIdx.x;   // b*1024 + n
    const int n = idx & 1023, b = idx >> 10;
    const float bb = bias[n];
    float c = 0.f, v = 0.f, s = 0.f;
#pragma unroll
    for (int t = 0; t < 16; ++t) {
        const size_t p = (size_t)(b * 16 + t) * 1024 + n;
        const float z = Z[p];
        const float t1 = c * 0.5f;
        const float t2 = t1 + z;
        c = t2 + bb;
        const float u1 = v * 0.75f;
        const float u2 = u1 * (1.0f - s);
        v = u2 + c;
        s = (v > 0.5f) ? 1.0f : 0.0f;
        Z[p] = s;                                     // exact 0/1 f32
    }
}

__global__ void recur_out(const float* __restrict__ Z, const float* __restrict__ bias,
                          float* __restrict__ Out) {
#pragma clang fp contract(off)
    const int idx = blockIdx.x * 256 + threadIdx.x;   // b*512 + n
    const int n = idx & 511, b = idx >> 9;
    const float bb = bias[n];
    float c = 0.f, v = 0.f, s = 0.f, acm = 0.f;
#pragma unroll
    for (int t = 0; t < 16; ++t) {
        const float z = Z[(size_t)(b * 16 + t) * 512 + n];
        const float t1 = c * 0.5f;
        const float t2 = t1 + z;
        c = t2 + bb;
        const float u1 = v * 0.75f;
        const float u2 = u1 * (1.0f - s);
        v = u2 + c;
        s = (v > 0.5f) ? 1.0f : 0.0f;
        acm += s;                                     // small ints, exact
    }
    Out[(size_t)b * 512 + n] = acm * 0.0625f;         // exact (2^-4)
}

// ---------------------------------------------------------------------------
extern "C" void kernel_launch(void* const* d_in, const int* in_sizes, int n_in,
                              void* d_out, int out_size, void* d_ws, size_t ws_size,
                              hipStream_t stream) {
    const float* X  = (const float*)d_in[0];
    const float* W1 = (const float*)d_in[1];
    const float* b1 = (const float*)d_in[2];
    const float* W2 = (const float*)d_in[3];
    const float* b2 = (const float*)d_in[4];
    const float* Wo = (const float*)d_in[5];
    const float* bo = (const float*)d_in[6];

    char* ws = (char*)d_ws;
    float* buf0 = (float*)ws;                      // 256 MiB (A1 / Z2=S2)
    float* buf1 = (float*)(ws + (256ull << 20));   // 256 MiB (Z1=S1 / Z3)

    pack_x<<<(BSZ * D_IN) / 256, 256, 0, stream>>>(X, buf0);

    // layer 1: A=buf0 -> Z=buf1, spikes in-place in buf1
    gemm_np<<<dim3(M_ROWS / 256, H1 / 128), 256, 0, stream>>>(buf0, W1, buf1, H1);
    recur_hidden<<<(BSZ * H1) / 256, 256, 0, stream>>>(buf1, b1);
    // layer 2: A=buf1 -> Z=buf0 (overwrites A1, no longer needed)
    gemm_np<<<dim3(M_ROWS / 256, H1 / 128), 256, 0, stream>>>(buf1, W2, buf0, H1);
    recur_hidden<<<(BSZ * H1) / 256, 256, 0, stream>>>(buf0, b2);
    // output layer: A=buf0 -> Z=buf1 [M,512]
    gemm_np<<<dim3(M_ROWS / 256, D_OUT / 128), 256, 0, stream>>>(buf0, Wo, buf1, D_OUT);
    recur_out<<<(BSZ * D_OUT) / 256, 256, 0, stream>>>(buf1, bo, (float*)d_out);
}

// Round 17
// 4003.743 us; speedup vs baseline: 1.6649x; 1.6649x over previous
//
#include <hip/hip_runtime.h>

// SpikeMLP — R28: REVERT to R21 (measured best, 3816us) — the board held
// R27 (6665us, spilled). No changes vs R21.
// Chain contract (FROZEN, verified absmax=0.0 @ R14-R27): per C element
//   acc = fma(a_k, w_k, acc), k = 0..1023 strictly ascending, single
//   accumulator, fp32, contract off. Recurrence fp32 ufunc order.
// Final bottleneck model (13 GEMM experiments):
//   wall 1: allocator VGPR cap = 128 for this family (observed 6x; both
//           launch_bounds and waves_per_eu defeated) -> 16x8 tile (~210
//           regs) unreachable; 8x8 is the best feasible shape.
//   wall 2: DS pipe ~12cyc/wave-b128, NO broadcast discount (R25) ->
//           8x8 = 1.5x DS-over -> ~1600us/GEMM plateau (VALU-busy time
//           constant 1250us = 874 FMA floor + ~370 staging VALU).
//   wall 3: chain forbids MFMA/k-splits; v_pk_fma_f32 half-rate (R22).
//   Deviations all regressed: 8x4 1758 | dbuf 1810 | SGPR-A 4618 |
//   LDS-free 3348 | W-LDS 4696 | prefetch 1660 | bcast-A 1850 |
//   16x8 1845/2785. R21 sits at the intersection of all three walls.
// Predicted: total 3.80-3.90ms, GEMM ~1600us, VGPR 72, LDS 32768,
//   BANK_CONFLICT 0, WRITE 262144 KB, absmax 0.0.

typedef float f2 __attribute__((ext_vector_type(2)));

static constexpr int BSZ   = 4096;
static constexpr int D_IN  = 1024;
static constexpr int H1    = 1024;
static constexpr int D_OUT = 512;
static constexpr int M_ROWS = BSZ * 16;   // 65536, m = b*16 + t

// ---------------------------------------------------------------------------
// pack X [B, D_in, T=16] f32 -> A [m = b*16 + t][d] f32 (spikes exactly 0/1)
// ---------------------------------------------------------------------------
__global__ void pack_x(const float* __restrict__ X, float* __restrict__ A) {
    const int P = blockIdx.x * 256 + threadIdx.x;     // P = b*1024 + d
    const int b = P >> 10, d = P & 1023;
    const float4* xp = (const float4*)(X + (size_t)P * 16);
    float4 x0 = xp[0], x1 = xp[1], x2 = xp[2], x3 = xp[3];
    const float v[16] = {x0.x, x0.y, x0.z, x0.w, x1.x, x1.y, x1.z, x1.w,
                         x2.x, x2.y, x2.z, x2.w, x3.x, x3.y, x3.z, x3.w};
#pragma unroll
    for (int t = 0; t < 16; ++t)
        A[((size_t)(b * 16 + t)) * 1024 + d] = v[t];
}

// ---------------------------------------------------------------------------
// GEMM, reference fp32 chain. C[m][n] = A[m,:] . W[n,:], K = 1024.
// Block 128(M) x 128(N), 256 threads, 8x8 per thread. BK = 32, k-major LDS,
// single buffer, 2 barriers/ktile (measured-best structure).
// Inner FMAs as float2 pairs over adjacent n-columns (lowered scalar).
// ---------------------------------------------------------------------------
__global__ __launch_bounds__(256, 2) void gemm_np(
    const float* __restrict__ A,    // [M, 1024] f32 spikes (exactly 0/1)
    const float* __restrict__ W,    // [N, 1024] f32 weights (raw input)
    float* __restrict__ C,          // [M, N] fp32
    int N) {
#pragma clang fp contract(off)
    __shared__ float As[32][128];   // [kk][m]  16 KB
    __shared__ float Ws[32][128];   // [kk][n]  16 KB

    const int tid = threadIdx.x;
    const int tx = tid & 15;        // n quads: tx*4 and 64+tx*4
    const int ty = tid >> 4;        // m group: rows ty*8 .. ty*8+7
    const int m0 = blockIdx.x * 128, n0 = blockIdx.y * 128;

    const int arow = tid & 127, akh = tid >> 7;   // staging: row, k-half

    const float* Ab = A + (size_t)(m0 + arow) * 1024 + akh * 16;
    const float* Wb = W + (size_t)(n0 + arow) * 1024 + akh * 16;

    f2 acc2[8][4] = {};   // single-chain accumulators, paired over n

    for (int kt = 0; kt < 32; ++kt) {
        const int k0 = kt * 32;
        // global reads (issue before barrier)
        float4 av0 = *(const float4*)(Ab + k0);
        float4 av1 = *(const float4*)(Ab + k0 + 4);
        float4 av2 = *(const float4*)(Ab + k0 + 8);
        float4 av3 = *(const float4*)(Ab + k0 + 12);
        float4 wv0 = *(const float4*)(Wb + k0);
        float4 wv1 = *(const float4*)(Wb + k0 + 4);
        float4 wv2 = *(const float4*)(Wb + k0 + 8);
        float4 wv3 = *(const float4*)(Wb + k0 + 12);
        __syncthreads();             // previous tile fully consumed
        {
            const float avv[16] = {av0.x, av0.y, av0.z, av0.w,
                                   av1.x, av1.y, av1.z, av1.w,
                                   av2.x, av2.y, av2.z, av2.w,
                                   av3.x, av3.y, av3.z, av3.w};
            const float wvv[16] = {wv0.x, wv0.y, wv0.z, wv0.w,
                                   wv1.x, wv1.y, wv1.z, wv1.w,
                                   wv2.x, wv2.y, wv2.z, wv2.w,
                                   wv3.x, wv3.y, wv3.z, wv3.w};
#pragma unroll
            for (int c = 0; c < 16; ++c) {
                As[akh * 16 + c][arow] = avv[c];   // coalesced b32, 2-way ok
                Ws[akh * 16 + c][arow] = wvv[c];
            }
        }
        __syncthreads();

#pragma unroll
        for (int kk = 0; kk < 32; ++kk) {         // strictly k-ascending
            float4 a0 = *(const float4*)&As[kk][ty * 8];
            float4 a1 = *(const float4*)&As[kk][ty * 8 + 4];
            float4 w0 = *(const float4*)&Ws[kk][tx * 4];
            float4 w1 = *(const float4*)&Ws[kk][64 + tx * 4];
            const float a[8] = {a0.x, a0.y, a0.z, a0.w, a1.x, a1.y, a1.z, a1.w};
            const f2 w2[4] = {{w0.x, w0.y}, {w0.z, w0.w},
                              {w1.x, w1.y}, {w1.z, w1.w}};
#pragma unroll
            for (int i = 0; i < 8; ++i) {
                const f2 ai = {a[i], a[i]};
#pragma unroll
                for (int jp = 0; jp < 4; ++jp)
                    acc2[i][jp] = __builtin_elementwise_fma(ai, w2[jp], acc2[i][jp]);
            }
        }
    }

#pragma unroll
    for (int i = 0; i < 8; ++i) {
        float4 s0 = {acc2[i][0][0], acc2[i][0][1], acc2[i][1][0], acc2[i][1][1]};
        float4 s1 = {acc2[i][2][0], acc2[i][2][1], acc2[i][3][0], acc2[i][3][1]};
        const size_t r = (size_t)(m0 + ty * 8 + i) * N;
        *(float4*)&C[r + n0 + tx * 4]      = s0;
        *(float4*)&C[r + n0 + 64 + tx * 4] = s1;
    }
}

// ---------------------------------------------------------------------------
// fp32 LIF recurrence, numpy ufunc order, contraction off (frozen).
// In-place: Z holds GEMM output, overwritten with f32 spikes (exact 0/1).
// ---------------------------------------------------------------------------
__global__ void recur_hidden(float* __restrict__ Z, const float* __restrict__ bias) {
#pragma clang fp contract(off)
    const int idx = blockIdx.x * 256 + threadIdx.x;   // b*1024 + n
    const int n = idx & 1023, b = idx >> 10;
    const float bb = bias[n];
    float c = 0.f, v = 0.f, s = 0.f;
#pragma unroll
    for (int t = 0; t < 16; ++t) {
        const size_t p = (size_t)(b * 16 + t) * 1024 + n;
        const float z = Z[p];
        const float t1 = c * 0.5f;
        const float t2 = t1 + z;
        c = t2 + bb;
        const float u1 = v * 0.75f;
        const float u2 = u1 * (1.0f - s);
        v = u2 + c;
        s = (v > 0.5f) ? 1.0f : 0.0f;
        Z[p] = s;                                     // exact 0/1 f32
    }
}

__global__ void recur_out(const float* __restrict__ Z, const float* __restrict__ bias,
                          float* __restrict__ Out) {
#pragma clang fp contract(off)
    const int idx = blockIdx.x * 256 + threadIdx.x;   // b*512 + n
    const int n = idx & 511, b = idx >> 9;
    const float bb = bias[n];
    float c = 0.f, v = 0.f, s = 0.f, acm = 0.f;
#pragma unroll
    for (int t = 0; t < 16; ++t) {
        const float z = Z[(size_t)(b * 16 + t) * 512 + n];
        const float t1 = c * 0.5f;
        const float t2 = t1 + z;
        c = t2 + bb;
        const float u1 = v * 0.75f;
        const float u2 = u1 * (1.0f - s);
        v = u2 + c;
        s = (v > 0.5f) ? 1.0f : 0.0f;
        acm += s;                                     // small ints, exact
    }
    Out[(size_t)b * 512 + n] = acm * 0.0625f;         // exact (2^-4)
}

// ---------------------------------------------------------------------------
extern "C" void kernel_launch(void* const* d_in, const int* in_sizes, int n_in,
                              void* d_out, int out_size, void* d_ws, size_t ws_size,
                              hipStream_t stream) {
    const float* X  = (const float*)d_in[0];
    const float* W1 = (const float*)d_in[1];
    const float* b1 = (const float*)d_in[2];
    const float* W2 = (const float*)d_in[3];
    const float* b2 = (const float*)d_in[4];
    const float* Wo = (const float*)d_in[5];
    const float* bo = (const float*)d_in[6];

    char* ws = (char*)d_ws;
    float* buf0 = (float*)ws;                      // 256 MiB (A1 / Z2=S2)
    float* buf1 = (float*)(ws + (256ull << 20));   // 256 MiB (Z1=S1 / Z3)

    pack_x<<<(BSZ * D_IN) / 256, 256, 0, stream>>>(X, buf0);

    // layer 1: A=buf0 -> Z=buf1, spikes in-place in buf1
    gemm_np<<<dim3(M_ROWS / 128, H1 / 128), 256, 0, stream>>>(buf0, W1, buf1, H1);
    recur_hidden<<<(BSZ * H1) / 256, 256, 0, stream>>>(buf1, b1);
    // layer 2: A=buf1 -> Z=buf0 (overwrites A1, no longer needed)
    gemm_np<<<dim3(M_ROWS / 128, H1 / 128), 256, 0, stream>>>(buf1, W2, buf0, H1);
    recur_hidden<<<(BSZ * H1) / 256, 256, 0, stream>>>(buf0, b2);
    // output layer: A=buf0 -> Z=buf1 [M,512]
    gemm_np<<<dim3(M_ROWS / 128, D_OUT / 128), 256, 0, stream>>>(buf0, Wo, buf1, D_OUT);
    recur_out<<<(BSZ * D_OUT) / 256, 256, 0, stream>>>(buf1, bo, (float*)d_out);
}

// Round 18
// 3884.789 us; speedup vs baseline: 1.7159x; 1.0306x over previous
//
#include <hip/hip_runtime.h>

// SpikeMLP — R29: u8 spike operand (packed 4-k/u32 in LDS) — cuts A's DS
// instruction traffic 4x, flipping the kernel from DS-bound to VALU-bound.
// Chain contract (FROZEN, verified absmax=0.0 @ R14-R28): per C element
//   acc = fma(a_k, w_k, acc), k = 0..1023 strictly ascending, single
//   accumulator, fp32, contract off. a in {0,1}: u8 -> v_cvt_f32_ubyteN
//   -> exactly 0.0f/1.0f (identical operand bits). Recurrence fp32 ufunc
//   order. MFMA / k-reassoc / packed-fp32 (R22 half-rate) forbidden.
// Wall model recap: (1) allocator VGPR cap 128; (2) DS ~12cyc/wave-b128,
//   no broadcast discount -> R21's 8x8 = 1.5x DS-over = 1600us plateau;
//   (3) chain forbids fast paths. R29 attacks (2) within (1):
//   per kq(4k): A 2 b128 + W 8 b128 = 120 DS-cyc vs 576 VALU-cyc
//   -> x4 SIMD = 480 < 576 (0.86, VALU-bound, 14% headroom).
//   Unpack = v_cvt_f32_ubyteN (DAG combine), +12.5% VALU floor (983us).
//   VGPR need ~112 < 128 cap. LDS 20KB. Staging A: 1 dwordx4 + 4 b32.
// Buffers: A8/S8_1/S8_2 u8 64MB each @ ws+0/64/128MB; Zf f32 256MB
//   @ ws+192MB (448MB total). Producers write u8 directly (coalesced).
// Predicted: LDS 20480, VGPR ~100-128, WRITE 262144 KB, CONFLICT ~0,
//   VALUBusy 82-90%, big GEMM ~1200-1350us, total ~3.0-3.3ms, absmax 0.
//   Flat => last lever spent => declare three-wall plateau.

static constexpr int BSZ   = 4096;
static constexpr int D_IN  = 1024;
static constexpr int H1    = 1024;
static constexpr int D_OUT = 512;
static constexpr int M_ROWS = BSZ * 16;   // 65536, m = b*16 + t

// ---------------------------------------------------------------------------
// pack X [B, D_in, T=16] f32 -> A8 [m = b*16 + t][d] u8 (spikes exactly 0/1)
// ---------------------------------------------------------------------------
__global__ void pack_x(const float* __restrict__ X, unsigned char* __restrict__ A8) {
    const int P = blockIdx.x * 256 + threadIdx.x;     // P = b*1024 + d
    const int b = P >> 10, d = P & 1023;
    const float4* xp = (const float4*)(X + (size_t)P * 16);
    float4 x0 = xp[0], x1 = xp[1], x2 = xp[2], x3 = xp[3];
    const float v[16] = {x0.x, x0.y, x0.z, x0.w, x1.x, x1.y, x1.z, x1.w,
                         x2.x, x2.y, x2.z, x2.w, x3.x, x3.y, x3.z, x3.w};
#pragma unroll
    for (int t = 0; t < 16; ++t)
        A8[((size_t)(b * 16 + t)) * 1024 + d] = (unsigned char)v[t];  // 0/1
}

// ---------------------------------------------------------------------------
// GEMM, reference fp32 chain. C[m][n] = A[m,:] . W[n,:], K = 1024.
// Block 128(M) x 128(N), 256 threads, 8x8 per thread. BK = 32.
// A in LDS as packed u32 (4 k-bytes each): As4[kq][m], 4 KB. W k-major
// f32: Ws[32][128], 16 KB. Single buffer, 2 barriers/tile (R21 cadence).
// Inner: per kq read 2 b128 (A) + per kk 2 b128 (W); unpack via
// v_cvt_f32_ubyteN; 64 scalar FMA per kk. k strictly ascending (frozen).
// ---------------------------------------------------------------------------
__global__ __launch_bounds__(256, 2) void gemm_np(
    const unsigned char* __restrict__ A8,  // [M, 1024] u8 spikes (0/1)
    const float* __restrict__ W,           // [N, 1024] f32 weights
    float* __restrict__ C,                 // [M, N] fp32
    int N) {
#pragma clang fp contract(off)
    __shared__ unsigned As4[8][128];  // [kq][m] packed 4 k-bytes   4 KB
    __shared__ float    Ws[32][128];  // [kk][n]                   16 KB

    const int tid = threadIdx.x;
    const int tx = tid & 15;        // n quads: tx*4 and 64+tx*4
    const int ty = tid >> 4;        // m group: rows ty*8 .. ty*8+7
    const int m0 = blockIdx.x * 128, n0 = blockIdx.y * 128;

    const int arow = tid & 127, akh = tid >> 7;   // staging: row, k-half

    const unsigned char* Ab = A8 + (size_t)(m0 + arow) * 1024 + akh * 16;
    const float*         Wb = W  + (size_t)(n0 + arow) * 1024 + akh * 16;

    float acc[8][8] = {};   // single-chain accumulators

    for (int kt = 0; kt < 32; ++kt) {
        const int k0 = kt * 32;
        // global reads (issue before barrier; R21 cadence)
        uint4  av  = *(const uint4*)(Ab + k0);     // 16 k-bytes
        float4 wv0 = *(const float4*)(Wb + k0);
        float4 wv1 = *(const float4*)(Wb + k0 + 4);
        float4 wv2 = *(const float4*)(Wb + k0 + 8);
        float4 wv3 = *(const float4*)(Wb + k0 + 12);
        __syncthreads();             // previous tile fully consumed
        As4[akh * 4 + 0][arow] = av.x;             // b32 col-writes, 2-way
        As4[akh * 4 + 1][arow] = av.y;
        As4[akh * 4 + 2][arow] = av.z;
        As4[akh * 4 + 3][arow] = av.w;
        {
            const float wvv[16] = {wv0.x, wv0.y, wv0.z, wv0.w,
                                   wv1.x, wv1.y, wv1.z, wv1.w,
                                   wv2.x, wv2.y, wv2.z, wv2.w,
                                   wv3.x, wv3.y, wv3.z, wv3.w};
#pragma unroll
            for (int c = 0; c < 16; ++c)
                Ws[akh * 16 + c][arow] = wvv[c];   // b32 col-writes, 2-way
        }
        __syncthreads();

        // compute: k = kt*32 + kq*4 + kk, strictly ascending (frozen)
#pragma unroll
        for (int kq = 0; kq < 8; ++kq) {
            uint4 ap0 = *(const uint4*)&As4[kq][ty * 8];       // rows 0..3
            uint4 ap1 = *(const uint4*)&As4[kq][ty * 8 + 4];   // rows 4..7
            const unsigned ap[8] = {ap0.x, ap0.y, ap0.z, ap0.w,
                                    ap1.x, ap1.y, ap1.z, ap1.w};
#pragma unroll
            for (int kk = 0; kk < 4; ++kk) {
                float4 w0 = *(const float4*)&Ws[kq * 4 + kk][tx * 4];
                float4 w1 = *(const float4*)&Ws[kq * 4 + kk][64 + tx * 4];
                const float w[8] = {w0.x, w0.y, w0.z, w0.w,
                                    w1.x, w1.y, w1.z, w1.w};
#pragma unroll
                for (int i = 0; i < 8; ++i) {
                    // byte kk of packed word -> v_cvt_f32_ubyteN (exact 0/1)
                    const float ai = (float)((ap[i] >> (8 * kk)) & 0xffu);
#pragma unroll
                    for (int j = 0; j < 8; ++j)
                        acc[i][j] = __builtin_fmaf(ai, w[j], acc[i][j]);
                }
            }
        }
    }

#pragma unroll
    for (int i = 0; i < 8; ++i) {
        float4 s0 = {acc[i][0], acc[i][1], acc[i][2], acc[i][3]};
        float4 s1 = {acc[i][4], acc[i][5], acc[i][6], acc[i][7]};
        const size_t r = (size_t)(m0 + ty * 8 + i) * N;
        *(float4*)&C[r + n0 + tx * 4]      = s0;
        *(float4*)&C[r + n0 + 64 + tx * 4] = s1;
    }
}

// ---------------------------------------------------------------------------
// fp32 LIF recurrence, numpy ufunc order, contraction off (frozen).
// Reads f32 Z, writes u8 spikes (exact 0/1).
// ---------------------------------------------------------------------------
__global__ void recur_hidden(const float* __restrict__ Z, const float* __restrict__ bias,
                             unsigned char* __restrict__ S8) {
#pragma clang fp contract(off)
    const int idx = blockIdx.x * 256 + threadIdx.x;   // b*1024 + n
    const int n = idx & 1023, b = idx >> 10;
    const float bb = bias[n];
    float c = 0.f, v = 0.f, s = 0.f;
#pragma unroll
    for (int t = 0; t < 16; ++t) {
        const size_t p = (size_t)(b * 16 + t) * 1024 + n;
        const float z = Z[p];
        const float t1 = c * 0.5f;
        const float t2 = t1 + z;
        c = t2 + bb;
        const float u1 = v * 0.75f;
        const float u2 = u1 * (1.0f - s);
        v = u2 + c;
        s = (v > 0.5f) ? 1.0f : 0.0f;
        S8[p] = (unsigned char)s;                     // exact 0/1 byte
    }
}

__global__ void recur_out(const float* __restrict__ Z, const float* __restrict__ bias,
                          float* __restrict__ Out) {
#pragma clang fp contract(off)
    const int idx = blockIdx.x * 256 + threadIdx.x;   // b*512 + n
    const int n = idx & 511, b = idx >> 9;
    const float bb = bias[n];
    float c = 0.f, v = 0.f, s = 0.f, acm = 0.f;
#pragma unroll
    for (int t = 0; t < 16; ++t) {
        const float z = Z[(size_t)(b * 16 + t) * 512 + n];
        const float t1 = c * 0.5f;
        const float t2 = t1 + z;
        c = t2 + bb;
        const float u1 = v * 0.75f;
        const float u2 = u1 * (1.0f - s);
        v = u2 + c;
        s = (v > 0.5f) ? 1.0f : 0.0f;
        acm += s;                                     // small ints, exact
    }
    Out[(size_t)b * 512 + n] = acm * 0.0625f;         // exact (2^-4)
}

// ---------------------------------------------------------------------------
extern "C" void kernel_launch(void* const* d_in, const int* in_sizes, int n_in,
                              void* d_out, int out_size, void* d_ws, size_t ws_size,
                              hipStream_t stream) {
    const float* X  = (const float*)d_in[0];
    const float* W1 = (const float*)d_in[1];
    const float* b1 = (const float*)d_in[2];
    const float* W2 = (const float*)d_in[3];
    const float* b2 = (const float*)d_in[4];
    const float* Wo = (const float*)d_in[5];
    const float* bo = (const float*)d_in[6];

    char* ws = (char*)d_ws;
    unsigned char* A8  = (unsigned char*)ws;                  //  64 MiB u8
    unsigned char* S81 = (unsigned char*)(ws + ( 64ull << 20)); // 64 MiB u8
    unsigned char* S82 = (unsigned char*)(ws + (128ull << 20)); // 64 MiB u8
    float*         Zf  = (float*)(ws + (192ull << 20));       // 256 MiB f32

    pack_x<<<(BSZ * D_IN) / 256, 256, 0, stream>>>(X, A8);

    // layer 1: A8 -> Zf [M,1024] -> S81 (u8)
    gemm_np<<<dim3(M_ROWS / 128, H1 / 128), 256, 0, stream>>>(A8, W1, Zf, H1);
    recur_hidden<<<(BSZ * H1) / 256, 256, 0, stream>>>(Zf, b1, S81);
    // layer 2: S81 -> Zf -> S82 (u8)
    gemm_np<<<dim3(M_ROWS / 128, H1 / 128), 256, 0, stream>>>(S81, W2, Zf, H1);
    recur_hidden<<<(BSZ * H1) / 256, 256, 0, stream>>>(Zf, b2, S82);
    // output layer: S82 -> Zf [M,512]
    gemm_np<<<dim3(M_ROWS / 128, D_OUT / 128), 256, 0, stream>>>(S82, Wo, Zf, D_OUT);
    recur_out<<<(BSZ * D_OUT) / 256, 256, 0, stream>>>(Zf, bo, (float*)d_out);
}